// Round 11
// baseline (104.569 us; speedup 1.0000x reference)
//
#include <hip/hip_runtime.h>
#include <hip/hip_bf16.h>

// SupCon loss, N=8192, D=128, T=0.1.
// R16: attack "rest". Budget fit across R8-R15: fill 41.5 (harness, fixed)
// + sweep ~24 + REST ~27 (constant every round; gaps ~1us per R8-vs-R9
// fusion A/B) => rest = norm_csum ~22 + finalize ~4. norm_csum's
// block-per-class shape serializes ~2-6 rows/wave x ~1800cy latency chains;
// worst class (~25 members) sets wall time. Fix:
//  - norm_rows: wave-per-row (2048 blocks, all rows in flight), class sums
//    via global atomicAdd csum[1024][128] (f32 adds of bf16-rounded vals =
//    same content as old LDS-atomic order, ulp-level reorder only).
//  - finalize2: wave-per-row computes cd = x.csum[lab], sd = x.x inline
//    (dual shfl), reads 16 separt partials, loss, 1 atomic per 8-wave
//    block. cd/sd/cm1 arrays deleted.
//  - hipMemsetAsync zeroes csum+count (capturable; harness memsets too).
// supcon_sweep: R15 VERBATIM (93.64us best, spill-free).
//
// Math: loss_i = (cm1_i*lse_i - 10*(cd_i - sd_i))/(cm1_i+tiny)
//   lse_i = 10 + ln(sum_{j!=i} e^{s_ij-10}); se accumulated INCLUDING
//   diagonal; diag e^{10*sd-10} subtracted in finalize. Singleton class:
//   csum == x bit-exact -> cd == sd -> loss 0 (matches reference).

typedef __bf16 bf16_t;
typedef __bf16 bf16x2 __attribute__((ext_vector_type(2)));
typedef __bf16 bf16x8 __attribute__((ext_vector_type(8)));
typedef float f32x16 __attribute__((ext_vector_type(16)));

#define NN 8192
#define DIM 128
#define SWEEP 16                  // column-sweep splits (partial arrays)
#define NCLS 1024                 // labels < 1000; padded
#define SMALL_VAL 1.17549435e-38f
#define L2E10 14.4269504089f      // 10*log2(e)
#define LN2 0.69314718056f

// Swizzle: X[row][d] at (row>>5)*4096 + (d>>4)*512 + ((d>>3)&1)*256 + (row&31)*8 + (d&7)
__device__ inline size_t swz(int row, int lane) {
    int f = lane >> 3, hh = (lane >> 2) & 1, j = (lane & 3) << 1;
    return ((size_t)(row >> 5) * 4096) + f * 512 + hh * 256 + (row & 31) * 8 + j;
}

// DPP-add step: v += dpp_perm(v). bound_ctrl=1 -> OOB lanes read 0.
#define DPPADD(v, ctrl, rmask)                                                         \
    do {                                                                               \
        int _t = __builtin_amdgcn_update_dpp(0, __float_as_int((v)), (ctrl), (rmask),  \
                                             0xf, true);                               \
        (v) += __int_as_float(_t);                                                     \
    } while (0)

// Sum over each 32-lane half; result valid in lane 31 (h=0) and lane 63 (h=1).
__device__ inline float half32_sum(float v) {
    DPPADD(v, 0x111, 0xf);   // row_shr:1
    DPPADD(v, 0x112, 0xf);   // row_shr:2
    DPPADD(v, 0x114, 0xf);   // row_shr:4
    DPPADD(v, 0x118, 0xf);   // row_shr:8
    DPPADD(v, 0x142, 0xa);   // row_bcast:15 into rows 1,3 -> lanes 31/63 full
    return v;
}

// async global->LDS, 16B per lane; LDS dest = uniform base + lane*16.
__device__ inline void gload_lds16(const bf16_t* g, bf16_t* l) {
    __builtin_amdgcn_global_load_lds(
        (const __attribute__((address_space(1))) unsigned int*)g,
        (__attribute__((address_space(3))) unsigned int*)l, 16, 0, 0);
}

// --- norm_rows: wave-per-row normalize + atomic class-sum ---
__global__ __launch_bounds__(256) void norm_rows(const float* __restrict__ emb,
                                                 const int* __restrict__ labels,
                                                 bf16_t* __restrict__ xsw,
                                                 float* __restrict__ csum,
                                                 int* __restrict__ count,
                                                 float* __restrict__ out) {
    int wv = threadIdx.x >> 6, lane = threadIdx.x & 63;
    int row = blockIdx.x * 4 + wv;
    if (blockIdx.x == 0 && threadIdx.x == 0) *out = 0.f;

    float2 v = ((const float2*)emb)[row * 64 + lane];
    float ss = fmaf(v.x, v.x, v.y * v.y);
#pragma unroll
    for (int m = 1; m < 64; m <<= 1) ss += __shfl_xor(ss, m, 64);
    float inv = 1.0f / fmaxf(sqrtf(ss), 1e-12f);
    bf16x2 o; o.x = (bf16_t)(v.x * inv); o.y = (bf16_t)(v.y * inv);
    *(bf16x2*)(xsw + swz(row, lane)) = o;

    int lab = labels[row];
    atomicAdd(&csum[lab * DIM + 2 * lane],     (float)o.x);  // bf16-rounded,
    atomicAdd(&csum[lab * DIM + 2 * lane + 1], (float)o.y);  // matches MFMA path
    if (lane == 0) atomicAdd(&count[lab], 1);
}

// --- main: 1024 blocks = (rb 0..63) x (s 0..15), 4 waves. Wave wv owns
// 32-row band I = rb*4+wv; sweeps chunks ch = s + 16*k, k=0..3 (128 cols).
// Double-buffered: issue next stage -> compute current -> one barrier.
// Full matrix; row sums complete in regs; plain stores. R15 VERBATIM.
// C layout (m74/m101): col = lane&31, row = (r&3)+8*(r>>2)+4*(lane>>5).
__global__
__attribute__((amdgpu_flat_work_group_size(256, 256)))
__attribute__((amdgpu_waves_per_eu(2, 2)))     // 256 unified/wave -> 128 arch
void supcon_sweep(const bf16_t* __restrict__ xsw,
                  float* __restrict__ se_part) {
    __shared__ bf16_t bst[2][4 * 4096];        // 2 x 32 KB -> 2 blocks/CU

    int s = blockIdx.x & 15, rb = blockIdx.x >> 4;
    int wv = threadIdx.x >> 6, lane = threadIdx.x & 63;
    int I = rb * 4 + wv;                       // 32-row band (0..255)
    int c = lane & 31, h = lane >> 5;
    int laneoff = h * 256 + c * 8;

    // A frags (global, L2-resident xsw): 32 VGPRs, loaded once
    const bf16_t* abase = xsw + (size_t)I * 4096 + laneoff;
    bf16x8 a[8];
#pragma unroll
    for (int f = 0; f < 8; ++f) a[f] = *(const bf16x8*)(abase + f * 512);

    float se[16];
#pragma unroll
    for (int r = 0; r < 16; ++r) se[r] = 0.f;

    // prologue: stage chunk 0 (ch = s) into buf 0; 8 x 1KB sub-chunks/wave
    {
        const bf16_t* gsrc = xsw + (size_t)s * 16384;
#pragma unroll
        for (int i = 0; i < 8; ++i) {
            int kk = i * 4 + wv;
            gload_lds16(gsrc + kk * 512 + lane * 8, &bst[0][kk * 512]);
        }
    }
    __syncthreads();                           // chunk 0 landed

#pragma unroll 1
    for (int k = 0; k < 4; ++k) {
        // issue NEXT chunk's stage first; lands under this chunk's compute
        if (k < 3) {
            const bf16_t* gsrc = xsw + (size_t)(s + 16 * (k + 1)) * 16384;
            bf16_t* dbuf = &bst[(k + 1) & 1][0];
#pragma unroll
            for (int i = 0; i < 8; ++i) {
                int kk = i * 4 + wv;
                gload_lds16(gsrc + kk * 512 + lane * 8, dbuf + kk * 512);
            }
        }
        const bf16_t* bb = &bst[k & 1][0];

#pragma unroll
        for (int t = 0; t < 4; ++t) {
            f32x16 acc;                        // single chain (R13's fit)
#pragma unroll
            for (int r = 0; r < 16; ++r) acc[r] = 0.f;
            const bf16_t* bt = bb + t * 4096 + laneoff;
#pragma unroll
            for (int f = 0; f < 8; ++f) {      // B frag read at use; 1 live tuple
                bf16x8 bfr = *(const bf16x8*)(bt + f * 512);
                acc = __builtin_amdgcn_mfma_f32_32x32x16_bf16(a[f], bfr, acc, 0, 0, 0);
            }
#pragma unroll
            for (int r = 0; r < 16; ++r)
                se[r] += __builtin_amdgcn_exp2f(fmaf(acc[r], L2E10, -L2E10));
        }
        // one barrier per chunk: (a) all waves done reading buf[k&1] before
        // its re-stage next iteration; (b) vmcnt drained -> prefetched
        // chunk complete (drain issued ~2500cy after the loads).
        __syncthreads();
    }

    // row sums: DPP reduce across 32 col-lanes; results in lane 31 (h=0)
    // and lane 63 (h=1). Plain stores, no atomics; (s,row) unique writer.
#pragma unroll
    for (int r = 0; r < 16; ++r) se[r] = half32_sum(se[r]);
    if (c == 31) {
        float* dst = se_part + (size_t)s * NN + I * 32 + 4 * h;
#pragma unroll
        for (int r = 0; r < 16; ++r)
            dst[(r & 3) + 8 * (r >> 2)] = se[r];
    }
}

// --- finalize2: wave-per-row; cd/sd inline, partial-sum gather, loss ---
__global__ __launch_bounds__(512) void finalize2(const bf16_t* __restrict__ xsw,
                                                 const float* __restrict__ se_part,
                                                 const float* __restrict__ csum,
                                                 const int* __restrict__ count,
                                                 const int* __restrict__ labels,
                                                 float* __restrict__ out) {
    __shared__ float part[8];
    int wv = threadIdx.x >> 6, lane = threadIdx.x & 63;
    int i = blockIdx.x * 8 + wv;               // row

    int lab = labels[i];
    bf16x2 xv = *(const bf16x2*)(xsw + swz(i, lane));
    float x0 = (float)xv.x, x1 = (float)xv.y;
    float2 cs2 = *(const float2*)(csum + lab * DIM + 2 * lane);
    float sp = (lane < SWEEP) ? se_part[(size_t)lane * NN + i] : 0.f;

    float cdp = fmaf(x0, cs2.x, x1 * cs2.y);
    float sdp = fmaf(x0, x0, x1 * x1);
#pragma unroll
    for (int m = 1; m < 64; m <<= 1) {
        cdp += __shfl_xor(cdp, m, 64);
        sdp += __shfl_xor(sdp, m, 64);
        sp  += __shfl_xor(sp,  m, 64);
    }
    if (lane == 0) {
        float cm1  = (float)(count[lab] - 1);
        float diag = __builtin_amdgcn_exp2f(fmaf(sdp, L2E10, -L2E10));
        float sev  = fmaxf(sp - diag, 1e-30f);
        float lse  = fmaf(__builtin_amdgcn_logf(sev), LN2, 10.f);   // v_log = log2
        part[wv] = (cm1 * lse - 10.f * (cdp - sdp)) / (cm1 + SMALL_VAL);
    }
    __syncthreads();
    if (threadIdx.x == 0) {
        float t = 0.f;
#pragma unroll
        for (int w = 0; w < 8; ++w) t += part[w];
        atomicAdd(out, t);                     // 1024 block-atomics, spread
    }
}

extern "C" void kernel_launch(void* const* d_in, const int* in_sizes, int n_in,
                              void* d_out, int out_size, void* d_ws, size_t ws_size,
                              hipStream_t stream) {
    const float* emb  = (const float*)d_in[0];
    const int* labels = (const int*)d_in[1];

    char* ws = (char*)d_ws;
    bf16_t* xsw   = (bf16_t*)ws;                          // 2 MB swizzled normalized X
    float* separt = (float*)(ws + (size_t)NN * DIM * 2);  // 512 KB (16 x 8192)
    float* csum   = separt + (size_t)SWEEP * NN;          // 512 KB (1024 x 128)
    int*   count  = (int*)(csum + (size_t)NCLS * DIM);    // 4 KB

    hipMemsetAsync(csum, 0, ((size_t)NCLS * DIM + NCLS) * sizeof(float), stream);
    norm_rows<<<NN / 4, 256, 0, stream>>>(emb, labels, xsw, csum, count, (float*)d_out);
    supcon_sweep<<<1024, 256, 0, stream>>>(xsw, separt);
    finalize2<<<NN / 8, 512, 0, stream>>>(xsw, separt, csum, count, labels, (float*)d_out);
}

// Round 12
// 97.284 us; speedup vs baseline: 1.0749x; 1.0749x over previous
//
#include <hip/hip_runtime.h>
#include <hip/hip_bf16.h>

// SupCon loss, N=8192, D=128, T=0.1.
// R17: halve the sweep's work via symmetry. R16 taught: norm_csum was ~3us
// all along (R8-vs-R9 proved launches ~free; bottom-up chain math); the
// constant ~21us is harness reset overhead. Budget: fill 41.5 + ovh 21 +
// norm 3 + fin 2 + SWEEP ~26. Only lever >= 2x: s_ij = s_ji, we compute
// all 67M entries. Circulant cover: tile (r, c=(r+d)%64), d=0..31 all r,
// + d=32 for r<32 => 2080 supertiles, each chunk-pair once. Block (r,p):
// d in {p,p+8,p+16,p+24} (+32 for p==0,r<32) -> 512 blocks (2/CU), 4-5
// tiles each. Row-side: registers -> rowpart[p][8192] (plain stores).
// Col-side (transposed): per-wave 128 col sums -> colW[(d-1)*4+wv][8192]
// UNIQUE-WRITER plain stores, no atomics (R16: 1M atomic RMWs ~ 10us),
// no zero-init (finalize reads exactly the written set; d=32 masked by
// i>=4096). R15's double-buffer pipeline + (2,2) tier kept (live ~75 arch
// vs 128 budget). norm_csum/loss-math identical to R15 (proven).
//
// Math: loss_i = (cm1_i*lse_i - 10*(cd_i - sd_i))/(cm1_i+tiny)
//   lse_i = 10 + ln(sum_{j!=i} e^{s_ij-10}); se accumulated INCLUDING
//   diagonal (d=0 tile covers own group fully; col-side skipped for d=0);
//   diag e^{10*sd-10} subtracted in finalize.

typedef __bf16 bf16_t;
typedef __bf16 bf16x2 __attribute__((ext_vector_type(2)));
typedef __bf16 bf16x8 __attribute__((ext_vector_type(8)));
typedef float f32x16 __attribute__((ext_vector_type(16)));

#define NN 8192
#define DIM 128
#define SMALL_VAL 1.17549435e-38f
#define L2E10 14.4269504089f      // 10*log2(e)
#define LN2 0.69314718056f

// Swizzle: X[row][d] at (row>>5)*4096 + (d>>4)*512 + ((d>>3)&1)*256 + (row&31)*8 + (d&7)
__device__ inline size_t swz(int row, int lane) {
    int f = lane >> 3, hh = (lane >> 2) & 1, j = (lane & 3) << 1;
    return ((size_t)(row >> 5) * 4096) + f * 512 + hh * 256 + (row & 31) * 8 + j;
}

// DPP-add step: v += dpp_perm(v). bound_ctrl=1 -> OOB lanes read 0.
#define DPPADD(v, ctrl, rmask)                                                         \
    do {                                                                               \
        int _t = __builtin_amdgcn_update_dpp(0, __float_as_int((v)), (ctrl), (rmask),  \
                                             0xf, true);                               \
        (v) += __int_as_float(_t);                                                     \
    } while (0)

// Sum over each 32-lane half; result valid in lane 31 (h=0) and lane 63 (h=1).
__device__ inline float half32_sum(float v) {
    DPPADD(v, 0x111, 0xf);   // row_shr:1
    DPPADD(v, 0x112, 0xf);   // row_shr:2
    DPPADD(v, 0x114, 0xf);   // row_shr:4
    DPPADD(v, 0x118, 0xf);   // row_shr:8
    DPPADD(v, 0x142, 0xa);   // row_bcast:15 into rows 1,3 -> lanes 31/63 full
    return v;
}

// async global->LDS, 16B per lane; LDS dest = uniform base + lane*16.
__device__ inline void gload_lds16(const bf16_t* g, bf16_t* l) {
    __builtin_amdgcn_global_load_lds(
        (const __attribute__((address_space(1))) unsigned int*)g,
        (__attribute__((address_space(3))) unsigned int*)l, 16, 0, 0);
}

// --- fused normalize + class-sum + per-row finalize scalars (R15 verbatim) ---
__global__ __launch_bounds__(256) void norm_csum(const float* __restrict__ emb,
                                                 const int* __restrict__ labels,
                                                 bf16_t* __restrict__ xsw,
                                                 float* __restrict__ cd_arr,
                                                 float* __restrict__ sd_arr,
                                                 float* __restrict__ cm1_arr,
                                                 float* __restrict__ out) {
    __shared__ float cs[DIM];
    __shared__ int rowlist[96];
    __shared__ int nrows;
    int cls = blockIdx.x;                      // 1024 blocks; labels < 1000
    int wv = threadIdx.x >> 6, lane = threadIdx.x & 63;
    if (threadIdx.x < DIM) cs[threadIdx.x] = 0.f;
    if (threadIdx.x == 0) nrows = 0;
    if (cls == 0 && threadIdx.x == 0) *out = 0.f;
    __syncthreads();

    float s0 = 0.f, s1 = 0.f;
    const int4* lab4 = (const int4*)(labels + wv * 2048);       // wave's quarter
#pragma unroll
    for (int it = 0; it < 8; ++it) {
        int4 l = lab4[it * 64 + lane];
        int base = wv * 2048 + it * 256;
#pragma unroll
        for (int cmp = 0; cmp < 4; ++cmp) {
            int li = (cmp == 0) ? l.x : (cmp == 1) ? l.y : (cmp == 2) ? l.z : l.w;
            unsigned long long m = __ballot(li == cls);
            while (m) {                         // wave-uniform loop, ~2 rows/wave avg
                int bb = __builtin_ctzll(m);
                m &= m - 1;
                int row = base + 4 * bb + cmp;
                float2 v = ((const float2*)emb)[row * 64 + lane];
                float ss = fmaf(v.x, v.x, v.y * v.y);
#pragma unroll
                for (int mm = 1; mm < 64; mm <<= 1) ss += __shfl_xor(ss, mm, 64);
                float inv = 1.0f / fmaxf(sqrtf(ss), 1e-12f);
                bf16x2 o; o.x = (bf16_t)(v.x * inv); o.y = (bf16_t)(v.y * inv);
                *(bf16x2*)(xsw + swz(row, lane)) = o;
                s0 += (float)o.x; s1 += (float)o.y;     // bf16-rounded, matches MFMA
                if (lane == 0) {
                    int idx = atomicAdd(&nrows, 1);
                    if (idx < 96) rowlist[idx] = row;
                }
            }
        }
    }
    atomicAdd(&cs[2 * lane], s0);
    atomicAdd(&cs[2 * lane + 1], s1);
    __syncthreads();
    int n = nrows;
    for (int k = wv; k < n; k += 4) {          // per-row cd/sd (rows split over waves)
        int row = rowlist[k];
        bf16x2 xv = *(const bf16x2*)(xsw + swz(row, lane));
        float x0 = (float)xv.x, x1 = (float)xv.y;
        float cdp = fmaf(x0, cs[2 * lane], x1 * cs[2 * lane + 1]);
        float sdp = fmaf(x0, x0, x1 * x1);
#pragma unroll
        for (int mm = 1; mm < 64; mm <<= 1) {
            cdp += __shfl_xor(cdp, mm, 64);
            sdp += __shfl_xor(sdp, mm, 64);
        }
        if (lane == 0) {
            cd_arr[row] = cdp; sd_arr[row] = sdp; cm1_arr[row] = (float)(n - 1);
        }
    }
}

// --- main: triangular circulant sweep. 512 blocks = (r 0..63) x (p 0..7),
// 4 waves. Wave wv owns band I = r*4+wv (rows I*32..+31). Chunk list:
// d in {p, p+8, p+16, p+24} (+ d=32 if p==0 && r<32); col chunk c=(r+d)%64.
// Row-side in regs -> rowpart[p][row]. Col-side (d>0): per-wave 128 col
// sums -> colW[(d-1)*4+wv][c*128+..] unique-writer plain stores.
// C layout (m74/m101): col = lane&31, row = (r&3)+8*(r>>2)+4*(lane>>5).
__global__
__attribute__((amdgpu_flat_work_group_size(256, 256)))
__attribute__((amdgpu_waves_per_eu(2, 2)))     // 256 unified/wave -> 128 arch
void supcon_tri(const bf16_t* __restrict__ xsw,
                float* __restrict__ rowpart,
                float* __restrict__ colW) {
    __shared__ bf16_t bst[2][4 * 4096];        // 2 x 32 KB -> 2 blocks/CU

    int p = blockIdx.x & 7, r = blockIdx.x >> 3;
    int wv = threadIdx.x >> 6, lane = threadIdx.x & 63;
    int I = r * 4 + wv;                        // 32-row band (0..255)
    int c32 = lane & 31, h = lane >> 5;
    int laneoff = h * 256 + c32 * 8;
    int nd = 4 + ((p == 0 && r < 32) ? 1 : 0); // 4 or 5 supertiles

    // A frags (global, L2-resident xsw): 32 VGPRs, loaded once
    const bf16_t* abase = xsw + (size_t)I * 4096 + laneoff;
    bf16x8 a[8];
#pragma unroll
    for (int f = 0; f < 8; ++f) a[f] = *(const bf16x8*)(abase + f * 512);

    float se[16];
#pragma unroll
    for (int rr = 0; rr < 16; ++rr) se[rr] = 0.f;

    // prologue: stage chunk for d0 = p into buf 0
    {
        const bf16_t* gsrc = xsw + (size_t)(((r + p) & 63)) * 16384;
#pragma unroll
        for (int i = 0; i < 8; ++i) {
            int kk = i * 4 + wv;
            gload_lds16(gsrc + kk * 512 + lane * 8, &bst[0][kk * 512]);
        }
    }
    __syncthreads();                           // chunk 0 landed

#pragma unroll 1
    for (int ki = 0; ki < nd; ++ki) {
        int d = (ki < 4) ? (p + 8 * ki) : 32;
        int cc = (r + d) & 63;                 // current col chunk
        // issue NEXT chunk's stage; lands under this chunk's compute
        if (ki + 1 < nd) {
            int dn = (ki + 1 < 4) ? (p + 8 * (ki + 1)) : 32;
            const bf16_t* gsrc = xsw + (size_t)((r + dn) & 63) * 16384;
            bf16_t* dbuf = &bst[(ki + 1) & 1][0];
#pragma unroll
            for (int i = 0; i < 8; ++i) {
                int kk = i * 4 + wv;
                gload_lds16(gsrc + kk * 512 + lane * 8, dbuf + kk * 512);
            }
        }
        const bf16_t* bb = &bst[ki & 1][0];

        float colsum[4];
#pragma unroll
        for (int t = 0; t < 4; ++t) {
            f32x16 acc;
#pragma unroll
            for (int rr = 0; rr < 16; ++rr) acc[rr] = 0.f;
            const bf16_t* bt = bb + t * 4096 + laneoff;
#pragma unroll
            for (int f = 0; f < 8; ++f) {      // B frag read at use; 1 live tuple
                bf16x8 bfr = *(const bf16x8*)(bt + f * 512);
                acc = __builtin_amdgcn_mfma_f32_32x32x16_bf16(a[f], bfr, acc, 0, 0, 0);
            }
            float cst = 0.f;
#pragma unroll
            for (int rr = 0; rr < 16; ++rr) {
                float e = __builtin_amdgcn_exp2f(fmaf(acc[rr], L2E10, -L2E10));
                se[rr] += e;
                cst += e;
            }
            colsum[t] = cst;
        }
        if (d != 0) {                          // wave-uniform; transposed side
#pragma unroll
            for (int t = 0; t < 4; ++t) {
                float v = colsum[t] + __shfl_xor(colsum[t], 32, 64);
                if (h == 0)
                    colW[(size_t)(((d - 1) << 2) + wv) * NN + cc * 128 + t * 32 + c32] = v;
            }
        }
        // one barrier per chunk: all waves done reading buf[ki&1] before its
        // re-stage; vmcnt drained -> prefetched chunk complete.
        __syncthreads();
    }

    // row sums: DPP reduce across 32 col-lanes; results in lane 31 (h=0)
    // and lane 63 (h=1). Plain stores; (p,row) unique writer.
#pragma unroll
    for (int rr = 0; rr < 16; ++rr) se[rr] = half32_sum(se[rr]);
    if (c32 == 31) {
        float* dst = rowpart + (size_t)p * NN + I * 32 + 4 * h;
#pragma unroll
        for (int rr = 0; rr < 16; ++rr)
            dst[(rr & 3) + 8 * (rr >> 2)] = se[rr];
    }
}

// --- finalize: sum 8 rowparts + 124/128 colparts, loss, block reduce ---
__global__ __launch_bounds__(256) void finalize_tri(const float* __restrict__ rowpart,
                                                    const float* __restrict__ colW,
                                                    const float* __restrict__ cd_arr,
                                                    const float* __restrict__ sd_arr,
                                                    const float* __restrict__ cm1_arr,
                                                    float* __restrict__ out) {
    __shared__ float part[4];
    int i = blockIdx.x * 256 + threadIdx.x;    // row
    float sev_raw = 0.f;
#pragma unroll
    for (int pp = 0; pp < 8; ++pp) sev_raw += rowpart[(size_t)pp * NN + i];
    int lim = (i >= 4096) ? 128 : 124;         // d=32 colparts exist only for g>=32
#pragma unroll 4
    for (int j = 0; j < 124; ++j) sev_raw += colW[(size_t)j * NN + i];
    if (lim == 128) {
#pragma unroll
        for (int j = 124; j < 128; ++j) sev_raw += colW[(size_t)j * NN + i];
    }
    float sd = sd_arr[i], cd = cd_arr[i], cm1 = cm1_arr[i];
    float diag = __builtin_amdgcn_exp2f(fmaf(sd, L2E10, -L2E10));
    float sev  = fmaxf(sev_raw - diag, 1e-30f);
    float lse  = fmaf(__builtin_amdgcn_logf(sev), LN2, 10.f);   // v_log = log2
    float loss = (cm1 * lse - 10.f * (cd - sd)) / (cm1 + SMALL_VAL);
#pragma unroll
    for (int m = 1; m < 64; m <<= 1) loss += __shfl_xor(loss, m, 64);
    int wv = threadIdx.x >> 6;
    if ((threadIdx.x & 63) == 0) part[wv] = loss;
    __syncthreads();
    if (threadIdx.x == 0) atomicAdd(out, part[0] + part[1] + part[2] + part[3]);
}

extern "C" void kernel_launch(void* const* d_in, const int* in_sizes, int n_in,
                              void* d_out, int out_size, void* d_ws, size_t ws_size,
                              hipStream_t stream) {
    const float* emb  = (const float*)d_in[0];
    const int* labels = (const int*)d_in[1];

    char* ws = (char*)d_ws;
    bf16_t* xsw    = (bf16_t*)ws;                          // 2 MB swizzled normalized X
    float* rowpart = (float*)(ws + (size_t)NN * DIM * 2);  // 256 KB (8 x 8192)
    float* colW    = rowpart + (size_t)8 * NN;             // 4 MB (128 x 8192)
    float* cd      = colW + (size_t)128 * NN;              // 32 KB
    float* sd      = cd + NN;                              // 32 KB
    float* cm1     = sd + NN;                              // 32 KB

    norm_csum<<<1024, 256, 0, stream>>>(emb, labels, xsw, cd, sd, cm1, (float*)d_out);
    supcon_tri<<<512, 256, 0, stream>>>(xsw, rowpart, colW);
    finalize_tri<<<NN / 256, 256, 0, stream>>>(rowpart, colW, cd, sd, cm1, (float*)d_out);
}